// Round 1
// baseline (443.039 us; speedup 1.0000x reference)
//
#include <hip/hip_runtime.h>

#define S_MAX 36500.0f
#define S_MIN 0.01f

// One thread per batch column; serial scan over seq_len steps.
// U-deep software-pipelined prefetch of the (delta_t, rating) float2 stream.
template <int U>
__global__ __launch_bounds__(256) void anki_scan(
    const float* __restrict__ inputs,  // [seq_len][batch][2]
    const float* __restrict__ w,       // [7]
    float* __restrict__ out,           // [seq_len][batch][2] then [batch][2]
    int seq_len, int batch)
{
#pragma clang fp contract(off)
    const int b = blockIdx.x * blockDim.x + threadIdx.x;
    if (b >= batch) return;

    const float w0 = w[0], w1 = w[1], w2 = w[2], w3 = w[3];
    const float w4 = w[4], w5 = w[5], w6 = w[6];

    const float2* __restrict__ in2  = (const float2*)inputs;
    float2* __restrict__ out2       = (float2*)out;
    float2* __restrict__ fin2       = (float2*)out + (size_t)seq_len * batch;

    float ivl = 0.0f, ease = 0.0f;

    float2 buf[U], nxt[U];
#pragma unroll
    for (int u = 0; u < U; ++u) buf[u] = in2[(size_t)u * batch + b];

    for (int t = 0; t < seq_len; t += U) {
        const bool have_next = (t + U < seq_len);
        if (have_next) {
#pragma unroll
            for (int u = 0; u < U; ++u)
                nxt[u] = in2[(size_t)(t + U + u) * batch + b];
        }
#pragma unroll
        for (int u = 0; u < U; ++u) {
            const float delta_t = buf[u].x;
            const float rating  = buf[u].y;

            const bool is_first = (ivl == 0.0f) || (ease == 0.0f);

            float ne = ease;
            ne = (rating == 1.0f) ? ease - 0.2f  : ne;
            ne = (rating == 2.0f) ? ease - 0.15f : ne;
            ne = (rating == 4.0f) ? ease + 0.15f : ne;
            ne = fminf(fmaxf(ne, 1.3f), 5.5f);

            const float days_late = delta_t - ivl;
            const bool pass_cond  = rating > 1.0f;
            const bool early      = pass_cond && (days_late <  0.0f);
            const bool non_early  = pass_cond && (days_late >= 0.0f);

            const float elapsed = ivl + days_late;
            const float e_hard  = fmaxf(elapsed * w4, ivl * w4 * 0.5f);
            const float e_good  = ivl * ne;
            const float e_easy  = e_good * w3;
            const float ivl_early =
                (rating == 2.0f) ? e_hard : ((rating == 4.0f) ? e_easy : e_good);

            const float n_hard = ivl * w4;
            const float n_good = (ivl + days_late * 0.5f)  * ne;
            const float n_easy = (ivl + days_late * 0.25f) * ne * w3;
            const float ivl_non_early =
                (rating == 2.0f) ? n_hard : ((rating == 4.0f) ? n_easy : n_good);

            const float calc =
                (early ? ivl_early : (non_early ? ivl_non_early : 0.0f)) * w6;

            float new_ivl = pass_cond ? calc : ivl;
            new_ivl = (rating == 1.0f) ? ivl * w5 : new_ivl;
            new_ivl = (is_first && rating <  4.0f) ? w0 : new_ivl;
            new_ivl = (is_first && rating == 4.0f) ? w1 : new_ivl;
            ne      = is_first ? w2 : ne;
            new_ivl = fminf(fmaxf(new_ivl, S_MIN), S_MAX);

            out2[(size_t)(t + u) * batch + b] = make_float2(new_ivl, ne);
            ivl = new_ivl;
            ease = ne;
        }
        if (have_next) {
#pragma unroll
            for (int u = 0; u < U; ++u) buf[u] = nxt[u];
        }
    }

    fin2[b] = make_float2(ivl, ease);
}

extern "C" void kernel_launch(void* const* d_in, const int* in_sizes, int n_in,
                              void* d_out, int out_size, void* d_ws, size_t ws_size,
                              hipStream_t stream) {
    const float* inputs = (const float*)d_in[0];
    const float* w      = (const float*)d_in[1];
    float* out          = (float*)d_out;

    const int seq_len = 512;
    const int batch   = in_sizes[0] / (seq_len * 2);  // 65536

    const int block = 256;
    const int grid  = (batch + block - 1) / block;
    anki_scan<8><<<grid, block, 0, stream>>>(inputs, w, out, seq_len, batch);
}

// Round 2
// 432.287 us; speedup vs baseline: 1.0249x; 1.0249x over previous
//
#include <hip/hip_runtime.h>

#define S_MAX 36500.0f
#define S_MIN 0.01f

// One thread per batch column; serial scan over seq_len steps.
// 16-deep software pipeline held entirely in NAMED scalar registers
// (no private arrays -> no scratch risk). seq_len must be a multiple of 16.
__global__ __launch_bounds__(256) void anki_scan(
    const float* __restrict__ inputs,  // [seq_len][batch][2]
    const float* __restrict__ w,       // [7]
    float* __restrict__ out,           // [seq_len][batch][2] then [batch][2]
    int seq_len, int batch)
{
#pragma clang fp contract(off)
    const int b = blockIdx.x * blockDim.x + threadIdx.x;
    if (b >= batch) return;

    const float w0 = w[0], w1 = w[1], w2 = w[2], w3 = w[3];
    const float w4 = w[4], w5 = w[5], w6 = w[6];

    const float2* __restrict__ in2  = (const float2*)inputs;
    float2* __restrict__ out2       = (float2*)out;
    float2* __restrict__ fin2       = (float2*)out + (size_t)seq_len * batch;

    float ivl = 0.0f, ease = 0.0f;

    auto step = [&](float2 x, int t_idx) {
        const float delta_t = x.x;
        const float rating  = x.y;

        const bool is_first = (ivl == 0.0f) || (ease == 0.0f);

        float ne = ease;
        ne = (rating == 1.0f) ? ease - 0.2f  : ne;
        ne = (rating == 2.0f) ? ease - 0.15f : ne;
        ne = (rating == 4.0f) ? ease + 0.15f : ne;
        ne = fminf(fmaxf(ne, 1.3f), 5.5f);

        const float days_late = delta_t - ivl;
        const bool pass_cond  = rating > 1.0f;
        const bool early      = pass_cond && (days_late <  0.0f);
        const bool non_early  = pass_cond && (days_late >= 0.0f);

        const float elapsed = ivl + days_late;
        const float e_hard  = fmaxf(elapsed * w4, ivl * w4 * 0.5f);
        const float e_good  = ivl * ne;
        const float e_easy  = e_good * w3;
        const float ivl_early =
            (rating == 2.0f) ? e_hard : ((rating == 4.0f) ? e_easy : e_good);

        const float n_hard = ivl * w4;
        const float n_good = (ivl + days_late * 0.5f)  * ne;
        const float n_easy = (ivl + days_late * 0.25f) * ne * w3;
        const float ivl_non_early =
            (rating == 2.0f) ? n_hard : ((rating == 4.0f) ? n_easy : n_good);

        const float calc =
            (early ? ivl_early : (non_early ? ivl_non_early : 0.0f)) * w6;

        float new_ivl = pass_cond ? calc : ivl;
        new_ivl = (rating == 1.0f) ? ivl * w5 : new_ivl;
        new_ivl = (is_first && rating <  4.0f) ? w0 : new_ivl;
        new_ivl = (is_first && rating == 4.0f) ? w1 : new_ivl;
        ne      = is_first ? w2 : ne;
        new_ivl = fminf(fmaxf(new_ivl, S_MIN), S_MAX);

        out2[(size_t)t_idx * batch + b] = make_float2(new_ivl, ne);
        ivl  = new_ivl;
        ease = ne;
    };

#define U16(M) M(0) M(1) M(2) M(3) M(4) M(5) M(6) M(7) \
               M(8) M(9) M(10) M(11) M(12) M(13) M(14) M(15)

    // Prologue: load group 0 into named registers.
#define DECL_C(i) float2 c##i = in2[(size_t)(i) * batch + b];
    U16(DECL_C)
#undef DECL_C

    int t = 0;
    for (; t + 16 < seq_len; t += 16) {
        // Issue all 16 next-group loads up front (stay in flight during compute).
#define DECL_N(i) float2 n##i = in2[(size_t)(t + 16 + (i)) * batch + b];
        U16(DECL_N)
#undef DECL_N

        // Compute + store current group (serial recurrence).
#define DO_STEP(i) step(c##i, t + (i));
        U16(DO_STEP)
#undef DO_STEP

        // Rotate buffers.
#define ROT(i) c##i = n##i;
        U16(ROT)
#undef ROT
    }

    // Epilogue: last group (t == seq_len - 16).
#define DO_STEP(i) step(c##i, t + (i));
    U16(DO_STEP)
#undef DO_STEP
#undef U16

    fin2[b] = make_float2(ivl, ease);
}

extern "C" void kernel_launch(void* const* d_in, const int* in_sizes, int n_in,
                              void* d_out, int out_size, void* d_ws, size_t ws_size,
                              hipStream_t stream) {
    const float* inputs = (const float*)d_in[0];
    const float* w      = (const float*)d_in[1];
    float* out          = (float*)d_out;

    const int seq_len = 512;
    const int batch   = in_sizes[0] / (seq_len * 2);  // 65536

    const int block = 256;
    const int grid  = (batch + block - 1) / block;
    anki_scan<<<grid, block, 0, stream>>>(inputs, w, out, seq_len, batch);
}